// Round 1
// baseline (161.329 us; speedup 1.0000x reference)
//
#include <hip/hip_runtime.h>

#define H 256
#define W 256
#define W4 (W / 4)            // 64 float4 per image row
#define OWID 250
#define OHEI 250
#define NIMG 256              // B*D
#define BAND 14               // output rows per wave (multiple of 7 for unroll)
#define NBANDS 18             // 17 full 14-row bands + one 12-row band
#define NBLK (NBANDS * NIMG)  // 4608 partials

__device__ __forceinline__ float4 f4zero() { return make_float4(0.f, 0.f, 0.f, 0.f); }

// s += n - o  (component-wise)
__device__ __forceinline__ void vacc(float4& s, const float4 n, const float4 o) {
    s.x += n.x - o.x; s.y += n.y - o.y; s.z += n.z - o.z; s.w += n.w - o.w;
}
// s += a*b - c*d  (component-wise)
__device__ __forceinline__ void vaccp(float4& s, const float4 a, const float4 b,
                                      const float4 c, const float4 d) {
    s.x += a.x * b.x - c.x * d.x;
    s.y += a.y * b.y - c.y * d.y;
    s.z += a.z * b.z - c.z * d.z;
    s.w += a.w * b.w - c.w * d.w;
}

__global__ __launch_bounds__(64) void ssim_band_kernel(
    const float* __restrict__ X, const float* __restrict__ Y,
    float* __restrict__ partial)
{
    // Single-wave block, NO LDS, NO barriers: the horizontal 7-tap neighbor
    // exchange is done with __shfl_down (ds_bpermute), so global prefetch
    // loads stay in flight across row iterations (no vmcnt(0) drain).
    const int lane = threadIdx.x;   // 0..63, owns cols 4*lane..4*lane+3
    const int band = blockIdx.x;    // 0..17
    const int img  = blockIdx.y;    // 0..255
    const int r0 = band * BAND;
    const int out_rows = (OHEI - r0 < BAND) ? (OHEI - r0) : BAND;
    const int rows_in = out_rows + 6;    // input rows this band (<= 20)

    const float4* Xp = (const float4*)X + ((size_t)img * H + r0) * W4 + lane;
    const float4* Yp = (const float4*)Y + ((size_t)img * H + r0) * W4 + lane;

    // 7-deep circular history of raw x,y (registers; all indices static).
    float4 xh[7], yh[7];
    float4 sx = f4zero(), sy = f4zero(), sxx = f4zero(), syy = f4zero(), sxy = f4zero();

    // Prologue: rows 0..5 fill history + vertical sums. Slot 6 = zeros so the
    // first main iteration (row 6) subtracts nothing.
    #pragma unroll
    for (int i = 0; i < 6; ++i) {
        float4 xv = Xp[i * W4];
        float4 yv = Yp[i * W4];
        xh[i] = xv; yh[i] = yv;
        vacc(sx, xv, f4zero());
        vacc(sy, yv, f4zero());
        vaccp(sxx, xv, xv, f4zero(), f4zero());
        vaccp(syy, yv, yv, f4zero(), f4zero());
        vaccp(sxy, xv, yv, f4zero(), f4zero());
    }
    xh[6] = f4zero(); yh[6] = f4zero();

    // Pre-load row 6.
    float4 xn = Xp[6 * W4];
    float4 yn = Yp[6 * W4];

    // SSIM constants with 1/49 and 49/48 folded in.
    const float C1  = 1e-4f;            // (0.01)^2
    const float C2  = 9e-4f;            // (0.03)^2
    const float AA  = 1.f / 2401.f;     // a^2          (a = 1/49)
    const float C2A = 2.f / 2401.f;     // 2 a^2
    const float T1  = 1.f / 24.f;       // 2 covn a     (covn = 49/48)
    const float T2  = -1.f / 1176.f;    // -2 covn a^2
    const float T3  = 1.f / 48.f;       // covn a
    const float T4  = -1.f / 2352.f;    // -covn a^2
    float lsum = 0.0f;

    // Outer step of 7 keeps base % 7 == 6 constant -> history index (6+i)%7
    // is a compile-time constant in the unrolled inner loop (no reg shifts).
    for (int base = 6; base < rows_in; base += 7) {
        #pragma unroll
        for (int i = 0; i < 7; ++i) {
            const int r = base + i;
            if (r < rows_in) {                 // wave-uniform guard
                const int slot = (6 + i) % 7;  // static
                // Prefetch next row early; consumed next iteration. No barrier
                // ever forces this to drain.
                float4 xf, yf;
                const bool more = (r + 1 < rows_in);
                if (more) { xf = Xp[(r + 1) * W4]; yf = Yp[(r + 1) * W4]; }

                // Vertical slide: add entering row, subtract leaving row.
                const float4 xo = xh[slot], yo = yh[slot];
                vacc(sx, xn, xo);
                vacc(sy, yn, yo);
                vaccp(sxx, xn, xn, xo, xo);
                vaccp(syy, yn, yn, yo, yo);
                vaccp(sxy, xn, yn, xo, yo);
                xh[slot] = xn; yh[slot] = yn;

                // Horizontal 7-tap sliding window via cross-lane shuffles.
                // Lane L, col s window = cols 4L+s .. 4L+s+6:
                //   needs lane L+1's 4 sums (b.*) and lane L+2's first 2 (c.*).
                // Out-of-range shuffles (lanes 62/63) return finite own values
                // and only feed columns masked by the OWID test below.
                float wx[4], wy[4], wxx[4], wyy[4], wxy[4];
                #define HWIN(S, WA)                                            \
                {                                                              \
                    const float bx = __shfl_down(S.x, 1);                      \
                    const float by = __shfl_down(S.y, 1);                      \
                    const float bz = __shfl_down(S.z, 1);                      \
                    const float bw = __shfl_down(S.w, 1);                      \
                    const float cx = __shfl_down(S.x, 2);                      \
                    const float cy = __shfl_down(S.y, 2);                      \
                    WA[0] = S.x + S.y + S.z + S.w + bx + by + bz;              \
                    WA[1] = WA[0] - S.x + bw;                                  \
                    WA[2] = WA[1] - S.y + cx;                                  \
                    WA[3] = WA[2] - S.z + cy;                                  \
                }
                HWIN(sx,  wx)
                HWIN(sy,  wy)
                HWIN(sxx, wxx)
                HWIN(syy, wyy)
                HWIN(sxy, wxy)
                #undef HWIN

                // SSIM for this lane's 4 output columns (constants folded).
                #pragma unroll
                for (int s = 0; s < 4; ++s) {
                    const float P  = wx[s] * wy[s];
                    const float Qs = fmaf(wy[s], wy[s], wx[s] * wx[s]);
                    const float Ws = wxx[s] + wyy[s];
                    const float A1 = fmaf(C2A, P, C1);
                    const float B1 = fmaf(AA, Qs, C1);
                    const float A2 = fmaf(T1, wxy[s], fmaf(T2, P, C2));
                    const float B2 = fmaf(T3, Ws, fmaf(T4, Qs, C2));
                    const float S  = (A1 * A2) * __builtin_amdgcn_rcpf(B1 * B2);
                    if (4 * lane + s < OWID) lsum += S;   // mask cols >= 250
                }
                xn = xf; yn = yf;
            }
        }
    }

    // Wave reduction -> one partial per block.
    #pragma unroll
    for (int off = 32; off > 0; off >>= 1)
        lsum += __shfl_down(lsum, off, 64);
    if (lane == 0) partial[img * NBANDS + band] = lsum;
}

__global__ __launch_bounds__(256) void ssim_reduce_kernel(
    const float* __restrict__ partial, float* __restrict__ out)
{
    const int tid = threadIdx.x;
    double acc = 0.0;
    for (int i = tid; i < NBLK; i += 256)
        acc += (double)partial[i];
    #pragma unroll
    for (int off = 32; off > 0; off >>= 1)
        acc += __shfl_down(acc, off, 64);
    __shared__ double wsumd[4];
    if ((tid & 63) == 0) wsumd[tid >> 6] = acc;
    __syncthreads();
    if (tid == 0) {
        double total = wsumd[0] + wsumd[1] + wsumd[2] + wsumd[3];
        float loss = (float)(1.0 - total / 16000000.0);
        out[0] = loss; out[1] = loss; out[2] = loss; out[3] = loss;
    }
}

extern "C" void kernel_launch(void* const* d_in, const int* in_sizes, int n_in,
                              void* d_out, int out_size, void* d_ws, size_t ws_size,
                              hipStream_t stream) {
    const float* X = (const float*)d_in[0];
    const float* Y = (const float*)d_in[1];
    // d_in[2] is the uniform 7x7 filter (1/49 everywhere) — constant-folded.
    float* out = (float*)d_out;
    float* partial = (float*)d_ws;   // 4608 floats = 18.4 KB

    hipLaunchKernelGGL(ssim_band_kernel, dim3(NBANDS, NIMG), dim3(64), 0, stream,
                       X, Y, partial);
    hipLaunchKernelGGL(ssim_reduce_kernel, dim3(1), dim3(256), 0, stream,
                       partial, out);
}

// Round 2
// 156.933 us; speedup vs baseline: 1.0280x; 1.0280x over previous
//
#include <hip/hip_runtime.h>

#define H 256
#define W 256
#define W4 (W / 4)            // 64 float4 per image row
#define OWID 250
#define NIMG 256              // B*D
#define BAND 10               // output rows per wave; 25*10 = 250 exactly
#define NBANDS 25
#define NBLK (NBANDS * NIMG)  // 6400 partials
#define RIN 16                // input rows per band: BAND + 6, uniform for ALL bands

__device__ __forceinline__ float4 f4zero() { return make_float4(0.f, 0.f, 0.f, 0.f); }

__global__ __launch_bounds__(64, 4) void ssim_band_kernel(
    const float* __restrict__ X, const float* __restrict__ Y,
    float* __restrict__ partial)
{
    // Single-wave block, no LDS, no barriers. Fully-unrolled 16-row band with
    // a depth-2 software prefetch pipeline: every history/pipeline index is a
    // compile-time constant (no scratch), and 2 row-pairs of global loads are
    // always in flight, hiding most of the ~900-cycle HBM latency per-wave.
    const int lane = threadIdx.x;   // 0..63, owns cols 4*lane..4*lane+3
    const int band = blockIdx.x;    // 0..24
    const int img  = blockIdx.y;    // 0..255
    const int r0 = band * BAND;

    const float4* Xp = (const float4*)X + ((size_t)img * H + r0) * W4 + lane;
    const float4* Yp = (const float4*)Y + ((size_t)img * H + r0) * W4 + lane;

    // 7-deep circular history of raw x,y (registers; all indices static).
    float4 xh[7], yh[7];
    // 4 vertical moments: sx, sy, sxy, and spp = Σ(x²+y²).
    // (uxx,uyy only ever appear in the SSIM formula as their SUM (vx+vy), so
    //  one merged moment replaces two — one fewer HWIN + fewer vertical ops.)
    float4 sx = f4zero(), sy = f4zero(), sxy = f4zero(), spp = f4zero();

    // Depth-2 prefetch pipeline.
    float4 px[2], py[2];
    px[0] = Xp[0];      py[0] = Yp[0];
    px[1] = Xp[W4];     py[1] = Yp[W4];
    xh[6] = f4zero();   yh[6] = f4zero();   // row-6 subtracts nothing

    // SSIM constants with 1/49 (=a) and 49/48 (=covn) folded in.
    const float C1  = 1e-4f;            // (0.01)^2
    const float C2  = 9e-4f;            // (0.03)^2
    const float AA  = 1.f / 2401.f;     // a^2
    const float C2A = 2.f / 2401.f;     // 2 a^2
    const float T1  = 1.f / 24.f;       // 2 covn a
    const float T2  = -1.f / 1176.f;    // -2 covn a^2
    const float T3  = 1.f / 48.f;       // covn a
    const float T4  = -1.f / 2352.f;    // -covn a^2
    float lsum = 0.0f;

    #pragma unroll
    for (int r = 0; r < RIN; ++r) {
        // Consume row r (loaded 2 iterations ago), then immediately refill the
        // slot with row r+2 so 2 row-pairs stay in flight.
        const float4 xn = px[r & 1], yn = py[r & 1];
        if (r + 2 < RIN) {
            px[r & 1] = Xp[(r + 2) * W4];
            py[r & 1] = Yp[(r + 2) * W4];
        }

        if (r < 6) {
            // Prologue rows: accumulate only.
            xh[r] = xn; yh[r] = yn;
            sx.x += xn.x; sx.y += xn.y; sx.z += xn.z; sx.w += xn.w;
            sy.x += yn.x; sy.y += yn.y; sy.z += yn.z; sy.w += yn.w;
            sxy.x = fmaf(xn.x, yn.x, sxy.x);
            sxy.y = fmaf(xn.y, yn.y, sxy.y);
            sxy.z = fmaf(xn.z, yn.z, sxy.z);
            sxy.w = fmaf(xn.w, yn.w, sxy.w);
            spp.x = fmaf(xn.x, xn.x, fmaf(yn.x, yn.x, spp.x));
            spp.y = fmaf(xn.y, xn.y, fmaf(yn.y, yn.y, spp.y));
            spp.z = fmaf(xn.z, xn.z, fmaf(yn.z, yn.z, spp.z));
            spp.w = fmaf(xn.w, xn.w, fmaf(yn.w, yn.w, spp.w));
        } else {
            const int slot = r % 7;            // static under full unroll
            const float4 xo = xh[slot], yo = yh[slot];

            // Vertical slide: + entering row r, - leaving row r-7.
            sx.x += xn.x - xo.x; sx.y += xn.y - xo.y;
            sx.z += xn.z - xo.z; sx.w += xn.w - xo.w;
            sy.x += yn.x - yo.x; sy.y += yn.y - yo.y;
            sy.z += yn.z - yo.z; sy.w += yn.w - yo.w;
            sxy.x = fmaf(xn.x, yn.x, fmaf(-xo.x, yo.x, sxy.x));
            sxy.y = fmaf(xn.y, yn.y, fmaf(-xo.y, yo.y, sxy.y));
            sxy.z = fmaf(xn.z, yn.z, fmaf(-xo.z, yo.z, sxy.z));
            sxy.w = fmaf(xn.w, yn.w, fmaf(-xo.w, yo.w, sxy.w));
            spp.x = fmaf(xn.x, xn.x, fmaf(yn.x, yn.x, fmaf(-xo.x, xo.x, fmaf(-yo.x, yo.x, spp.x))));
            spp.y = fmaf(xn.y, xn.y, fmaf(yn.y, yn.y, fmaf(-xo.y, xo.y, fmaf(-yo.y, yo.y, spp.y))));
            spp.z = fmaf(xn.z, xn.z, fmaf(yn.z, yn.z, fmaf(-xo.z, xo.z, fmaf(-yo.z, yo.z, spp.z))));
            spp.w = fmaf(xn.w, xn.w, fmaf(yn.w, yn.w, fmaf(-xo.w, xo.w, fmaf(-yo.w, yo.w, spp.w))));
            xh[slot] = xn; yh[slot] = yn;

            // Horizontal 7-tap sliding window via cross-lane shuffles.
            // Lane L col s window = cols 4L+s .. 4L+s+6: needs lane L+1's 4
            // sums and lane L+2's first 2. Out-of-range shuffles (lanes 62/63)
            // return own values and only feed columns masked below.
            float wx[4], wy[4], wpp[4], wxy[4];
            #define HWIN(S, WA)                                            \
            {                                                              \
                const float bx = __shfl_down(S.x, 1);                      \
                const float by = __shfl_down(S.y, 1);                      \
                const float bz = __shfl_down(S.z, 1);                      \
                const float bw = __shfl_down(S.w, 1);                      \
                const float cx = __shfl_down(S.x, 2);                      \
                const float cy = __shfl_down(S.y, 2);                      \
                WA[0] = S.x + S.y + S.z + S.w + bx + by + bz;              \
                WA[1] = WA[0] - S.x + bw;                                  \
                WA[2] = WA[1] - S.y + cx;                                  \
                WA[3] = WA[2] - S.z + cy;                                  \
            }
            HWIN(sx,  wx)
            HWIN(sy,  wy)
            HWIN(spp, wpp)
            HWIN(sxy, wxy)
            #undef HWIN

            // SSIM for this lane's 4 output columns (constants folded):
            //   A1 = 2a²·wx·wy + C1
            //   B1 = a²·(wx²+wy²) + C1
            //   A2 = 2covn·a·wxy − 2covn·a²·wx·wy + C2
            //   B2 = covn·a·wpp − covn·a²·(wx²+wy²) + C2
            #pragma unroll
            for (int s = 0; s < 4; ++s) {
                const float P  = wx[s] * wy[s];
                const float Qs = fmaf(wy[s], wy[s], wx[s] * wx[s]);
                const float A1 = fmaf(C2A, P, C1);
                const float B1 = fmaf(AA, Qs, C1);
                const float A2 = fmaf(T1, wxy[s], fmaf(T2, P, C2));
                const float B2 = fmaf(T3, wpp[s], fmaf(T4, Qs, C2));
                const float S  = (A1 * A2) * __builtin_amdgcn_rcpf(B1 * B2);
                if (4 * lane + s < OWID) lsum += S;   // mask cols >= 250
            }
        }
    }

    // Wave reduction -> one partial per block.
    #pragma unroll
    for (int off = 32; off > 0; off >>= 1)
        lsum += __shfl_down(lsum, off, 64);
    if (lane == 0) partial[img * NBANDS + band] = lsum;
}

__global__ __launch_bounds__(256) void ssim_reduce_kernel(
    const float* __restrict__ partial, float* __restrict__ out)
{
    const int tid = threadIdx.x;
    double acc = 0.0;
    for (int i = tid; i < NBLK; i += 256)
        acc += (double)partial[i];
    #pragma unroll
    for (int off = 32; off > 0; off >>= 1)
        acc += __shfl_down(acc, off, 64);
    __shared__ double wsumd[4];
    if ((tid & 63) == 0) wsumd[tid >> 6] = acc;
    __syncthreads();
    if (tid == 0) {
        double total = wsumd[0] + wsumd[1] + wsumd[2] + wsumd[3];
        float loss = (float)(1.0 - total / 16000000.0);
        out[0] = loss; out[1] = loss; out[2] = loss; out[3] = loss;
    }
}

extern "C" void kernel_launch(void* const* d_in, const int* in_sizes, int n_in,
                              void* d_out, int out_size, void* d_ws, size_t ws_size,
                              hipStream_t stream) {
    const float* X = (const float*)d_in[0];
    const float* Y = (const float*)d_in[1];
    // d_in[2] is the uniform 7x7 filter (1/49 everywhere) — constant-folded.
    float* out = (float*)d_out;
    float* partial = (float*)d_ws;   // 6400 floats = 25.6 KB

    hipLaunchKernelGGL(ssim_band_kernel, dim3(NBANDS, NIMG), dim3(64), 0, stream,
                       X, Y, partial);
    hipLaunchKernelGGL(ssim_reduce_kernel, dim3(1), dim3(256), 0, stream,
                       partial, out);
}